// Round 10
// baseline (117.406 us; speedup 1.0000x reference)
//
#include <hip/hip_runtime.h>
#include <hip/hip_fp16.h>

// FourierFilter: out = Re(IFFT(mask * FFT(x, axis=-1))), mask zeroes bins with
// |freq| < 10 Hz (kf <= 819 of 8192 @ 100 Hz). x: [64,128,8192] f32.
//
// Register-resident four-step FFT, two real rows packed per complex row.
// 256 threads x 32 complex regs (packed fp32 VALU via ext_vector_type(2)).
// Stage grouping 3+5+5: phase-1 chains {4t+e+1024m} (float4 global I/O),
// phase-2 chains {1024(t>>5)+(t&31)+32m}, phase-3 contiguous {32t+e} with
// fwd FFT-32 + MASK(brev13) + inv FFT-32 fused in registers.
// Inverse mirrors (conj pre-twiddle, DIT). 4 LDS RTs / 4 barriers.
//
// R9 change: LDS addressing switched from additive pad i+(i>>6) (33,280 B) to
// XOR swizzle phys(i) = i ^ ((i>>6)&31) (bijective, zero overhead): LDS is
// exactly 32,768 B -> 5 blocks/CU (5*32KB = 160KB pool exactly; was 4).
// Bank check (wave64, 4B elems): P1 banks (4b+e)^(C+a) all-32 2-way;
// P2 (l&31)^(16(l>>5)+D) all-32 2-way; P3 e^(l>>1) all-32 2-way. 2-way is
// free (m136); counter shows 1 cycle/LDS-instr, same as padded version.
// R6 lesson: shuffle-based stages regressed (VALUBusy 66%) — stay LDS-based.

#define FFT_N 8192
#define NT    256
#define PHY(i) ((i) ^ (((i) >> 6) & 31))

typedef float v2f __attribute__((ext_vector_type(2)));
typedef float v4f __attribute__((ext_vector_type(4)));

__device__ __forceinline__ v2f cmul(v2f a, v2f b){
  v2f axx = {a.x, a.x};
  v2f ayy = {a.y, a.y};
  v2f byx = {-b.y, b.x};
  return axx * b + ayy * byx;
}

// d * W_32^j (or conj), j in [0,16), compile-time after unroll -> constants fold.
__device__ __forceinline__ v2f mul_w32(v2f d, int j, bool cj){
  if (j == 0) return d;
  if (j == 8) return cj ? (v2f){-d.y, d.x} : (v2f){d.y, -d.x};
  const float C[16] = {1.f, 0.98078528f, 0.92387953f, 0.83146961f, 0.70710678f,
                       0.55557023f, 0.38268343f, 0.19509032f, 0.f, -0.19509032f,
                       -0.38268343f, -0.55557023f, -0.70710678f, -0.83146961f,
                       -0.92387953f, -0.98078528f};
  const float S[16] = {0.f, -0.19509032f, -0.38268343f, -0.55557023f, -0.70710678f,
                       -0.83146961f, -0.92387953f, -0.98078528f, -1.f, -0.98078528f,
                       -0.92387953f, -0.83146961f, -0.70710678f, -0.55557023f,
                       -0.38268343f, -0.19509032f};
  v2f w = {C[j], cj ? -S[j] : S[j]};
  return cmul(d, w);
}

// DIF radix-2 stages, spans L..1 over SZ regs. Stage twiddle W_{2L}^j == W_32^{j*16/L}.
template<int SZ, int L>
__device__ __forceinline__ void dif_rec(v2f* r){
  #pragma unroll
  for (int g = 0; g < SZ; g += 2*L){
    #pragma unroll
    for (int j = 0; j < L; ++j){
      v2f u = r[g+j], v = r[g+j+L];
      r[g+j]   = u + v;
      r[g+j+L] = mul_w32(u - v, j*(16/L), false);
    }
  }
  if constexpr (L > 1) dif_rec<SZ, L/2>(r);
}

// Inverse DIT radix-2 stages, spans 1..SZ/2 (conjugate twiddles), unnormalized.
template<int SZ, int L>
__device__ __forceinline__ void dit_rec(v2f* r){
  #pragma unroll
  for (int g = 0; g < SZ; g += 2*L){
    #pragma unroll
    for (int j = 0; j < L; ++j){
      v2f a = r[g+j];
      v2f b = mul_w32(r[g+j+L], j*(16/L), true);
      r[g+j]   = a + b;
      r[g+j+L] = a - b;
    }
  }
  if constexpr (2*L < SZ) dit_rec<SZ, 2*L>(r);
}

__host__ __device__ constexpr int brev5(int k){
  return ((k&1)<<4) | ((k&2)<<2) | (k&4) | ((k&8)>>2) | ((k&16)>>4);
}

// r[brev5(k)] *= W_8192^{cbase*k} (or conj), k=1..31 (two half-chains for ILP).
__device__ __forceinline__ void twiddle_scale(v2f* r, int cbase, bool cj){
  float s, c;
  __sincosf((float)cbase * -7.6699039394282061e-4f, &s, &c);  // -2*pi/8192
  if (cj) s = -s;
  const v2f w1 = {c, s};
  v2f w2q = cmul(w1, w1);
  v2f w4q = cmul(w2q, w2q);
  v2f w8q = cmul(w4q, w4q);
  v2f w16 = cmul(w8q, w8q);
  v2f wa = w1;
  r[brev5(1)]  = cmul(r[brev5(1)],  wa);
  r[brev5(17)] = cmul(r[brev5(17)], cmul(w16, wa));
  #pragma unroll
  for (int k = 2; k <= 15; ++k){
    wa = cmul(wa, w1);
    r[brev5(k)]    = cmul(r[brev5(k)],    wa);
    r[brev5(k+16)] = cmul(r[brev5(k+16)], cmul(w16, wa));
  }
  r[brev5(16)] = cmul(r[brev5(16)], w16);
}

// r[brev3(k)] *= w1^k, k=1..7, w1 = W_8192^c (pass conj(w1) for inverse).
// brev3: 1->4, 2->2, 3->6, 4->1, 5->5, 6->3, 7->7.
__device__ __forceinline__ void tw8(v2f* r, v2f w1){
  v2f w2 = cmul(w1, w1);
  v2f w3 = cmul(w2, w1);
  v2f w4 = cmul(w2, w2);
  v2f w5 = cmul(w4, w1);
  v2f w6 = cmul(w4, w2);
  v2f w7 = cmul(w4, w3);
  r[4] = cmul(r[4], w1);
  r[2] = cmul(r[2], w2);
  r[6] = cmul(r[6], w3);
  r[1] = cmul(r[1], w4);
  r[5] = cmul(r[5], w5);
  r[3] = cmul(r[3], w6);
  r[7] = cmul(r[7], w7);
}

__global__ __launch_bounds__(NT, 2)
void fourier_filter_kernel(const float* __restrict__ x, float* __restrict__ out){
  __shared__ __half2 zs[FFT_N];   // 8192 * 4B = 32 KB exactly -> 5 blocks/CU
  const int t = threadIdx.x;
  const long long pair = blockIdx.x;
  const float* r0 = x + pair * (2LL * FFT_N);
  const float* r1 = r0 + FFT_N;
  v2f r[32];

  // W_8192^1, W_8192^2 (for chain bases 4t+1, 4t+2, 4t+3)
  const v2f W1C = {0.9999997058629f, -7.669903187e-4f};
  const v2f W2C = {0.9999988234517f, -1.5339801863e-3f};

  // ---- fwd phase 1: 4 chains c=4t+e, FFT-8 over m (n = 4t+e+1024m) ----
  #pragma unroll
  for (int m = 0; m < 8; ++m){
    const int n = 4*t + (m << 10);
    const v4f a = *reinterpret_cast<const v4f*>(r0 + n);
    const v4f b = *reinterpret_cast<const v4f*>(r1 + n);
    r[0*8+m] = (v2f){a.x, b.x};
    r[1*8+m] = (v2f){a.y, b.y};
    r[2*8+m] = (v2f){a.z, b.z};
    r[3*8+m] = (v2f){a.w, b.w};
  }
  #pragma unroll
  for (int e = 0; e < 4; ++e) dif_rec<8, 4>(r + 8*e);
  {
    float s, c;
    __sincosf((float)(4*t) * -7.6699039394282061e-4f, &s, &c);
    v2f w0 = {c, s};
    v2f wA = cmul(w0, W1C);
    v2f wB = cmul(w0, W2C);
    v2f wC = cmul(wA, W2C);
    tw8(r + 0,  w0);
    tw8(r + 8,  wA);
    tw8(r + 16, wB);
    tw8(r + 24, wC);
  }
  #pragma unroll
  for (int e = 0; e < 4; ++e)
    #pragma unroll
    for (int m = 0; m < 8; ++m)
      zs[PHY(4*t + e + (m<<10))] = __floats2half2_rn(r[8*e+m].x, r[8*e+m].y);
  __syncthreads();

  // ---- fwd phase 2: chains {1024(t>>5) + (t&31) + 32m}, FFT-32 ----
  const int base2 = ((t >> 5) << 10) | (t & 31);
  #pragma unroll
  for (int m = 0; m < 32; ++m){
    float2 f = __half22float2(zs[PHY(base2 + (m<<5))]);
    r[m] = (v2f){f.x, f.y};
  }
  dif_rec<32, 16>(r);
  twiddle_scale(r, (t & 31) << 3, false);   // W_1024^{c2*k} = W_8192^{8*c2*k}
  #pragma unroll
  for (int m = 0; m < 32; ++m)
    zs[PHY(base2 + (m<<5))] = __floats2half2_rn(r[m].x, r[m].y);
  __syncthreads();

  // ---- phase 3: contiguous FFT-32 fwd + MASK + inv, fused in regs ----
  #pragma unroll
  for (int e = 0; e < 32; ++e){
    float2 f = __half22float2(zs[PHY((t<<5) + e)]);
    r[e] = (v2f){f.x, f.y};
  }
  dif_rec<32, 16>(r);
  #pragma unroll
  for (int e = 0; e < 32; ++e){
    const int v  = (t << 5) + e;
    const int k  = (int)(__brev((unsigned)v) >> 19);   // slot v holds bin brev13(v)
    const int kf = min(k, FFT_N - k);
    if (kf <= 819) r[e] = (v2f){0.f, 0.f};             // |freq| < 10 Hz
  }
  dit_rec<32, 1>(r);
  #pragma unroll
  for (int e = 0; e < 32; ++e)
    zs[PHY((t<<5) + e)] = __floats2half2_rn(r[e].x, r[e].y);
  __syncthreads();

  // ---- inv phase 2: conj pre-twiddle, DIT ----
  #pragma unroll
  for (int m = 0; m < 32; ++m){
    float2 f = __half22float2(zs[PHY(base2 + (m<<5))]);
    r[m] = (v2f){f.x, f.y};
  }
  twiddle_scale(r, (t & 31) << 3, true);
  dit_rec<32, 1>(r);
  #pragma unroll
  for (int m = 0; m < 32; ++m)
    zs[PHY(base2 + (m<<5))] = __floats2half2_rn(r[m].x, r[m].y);
  __syncthreads();

  // ---- inv phase 1: conj pre-twiddle, 4 x DIT-8, vec4 store ----
  #pragma unroll
  for (int e = 0; e < 4; ++e)
    #pragma unroll
    for (int m = 0; m < 8; ++m){
      float2 f = __half22float2(zs[PHY(4*t + e + (m<<10))]);
      r[8*e+m] = (v2f){f.x, f.y};
    }
  {
    float s, c;
    __sincosf((float)(4*t) * -7.6699039394282061e-4f, &s, &c);
    v2f w0 = {c, -s};                        // conj(W^{4t})
    const v2f W1Cc = {W1C.x, -W1C.y};
    const v2f W2Cc = {W2C.x, -W2C.y};
    v2f wA = cmul(w0, W1Cc);
    v2f wB = cmul(w0, W2Cc);
    v2f wC = cmul(wA, W2Cc);
    tw8(r + 0,  w0);
    tw8(r + 8,  wA);
    tw8(r + 16, wB);
    tw8(r + 24, wC);
  }
  #pragma unroll
  for (int e = 0; e < 4; ++e) dit_rec<8, 1>(r + 8*e);

  const float invn = 1.f / (float)FFT_N;
  float* o0 = out + pair * (2LL * FFT_N);
  float* o1 = o0 + FFT_N;
  #pragma unroll
  for (int m = 0; m < 8; ++m){
    const int n = 4*t + (m << 10);
    v4f a, b;
    a.x = r[0*8+m].x * invn;  b.x = r[0*8+m].y * invn;
    a.y = r[1*8+m].x * invn;  b.y = r[1*8+m].y * invn;
    a.z = r[2*8+m].x * invn;  b.z = r[2*8+m].y * invn;
    a.w = r[3*8+m].x * invn;  b.w = r[3*8+m].y * invn;
    __builtin_nontemporal_store(a, reinterpret_cast<v4f*>(o0 + n));
    __builtin_nontemporal_store(b, reinterpret_cast<v4f*>(o1 + n));
  }
}

extern "C" void kernel_launch(void* const* d_in, const int* in_sizes, int n_in,
                              void* d_out, int out_size, void* d_ws, size_t ws_size,
                              hipStream_t stream) {
  const float* x = (const float*)d_in[0];
  float* out = (float*)d_out;
  const int total  = in_sizes[0];              // 64*128*8192
  const int npairs = total / (2 * FFT_N);      // 4096 row pairs
  hipLaunchKernelGGL(fourier_filter_kernel, dim3(npairs), dim3(NT), 0, stream,
                     x, out);
}

// Round 11
// 104.293 us; speedup vs baseline: 1.1257x; 1.1257x over previous
//
#include <hip/hip_runtime.h>
#include <hip/hip_fp16.h>

// FourierFilter: out = Re(IFFT(mask * FFT(x, axis=-1))), mask zeroes bins with
// |freq| < 10 Hz (kf <= 819 of 8192 @ 100 Hz). x: [64,128,8192] f32.
//
// Register-resident four-step FFT, two real rows packed per complex row.
// 256 threads x 32 complex regs. Stage grouping 3+5+5: phase-1 chains
// {4t+e+1024m} (float4 global I/O), phase-2 chains {1024(t>>5)+(t&31)+32m},
// phase-3 contiguous {32t+e} with fwd FFT-32 + MASK(brev13) + inv FFT-32
// fused in registers. Inverse mirrors (conj pre-twiddle, DIT).
// 4 LDS RTs / 4 barriers. LDS fp16 __half2, additive pad i+(i>>6) (33,280 B,
// 4 blocks/CU). Loads cached; stores nontemporal (v4f for the builtin).
//
// R9 lesson: XOR-swizzle 32KB-exact -> 5 blocks/CU REGRESSED (108->117);
//   bank patterns identical by derivation, so 100% LDS-pool residency is the
//   poison. Reverted to pad + 4 blocks.
// R10 change: cmul via inline-asm VOP3P packed fp32:
//   v_pk_mul_f32  t, a, b  op_sel:[0,0]  op_sel_hi:[0,1]        (a.x * b)
//   v_pk_fma_f32  d, a, b, t op_sel:[1,1,0] op_sel_hi:[1,0,1]
//                 neg_lo:[0,1,0]           (+= a.y * (-b.y, b.x))
//   = exact complex multiply in 2 VALU ops (broadcast/swap/neg via modifiers).
//   VALUBusy model said compiler wasn't forming these (75us vs 44us ideal).

#define FFT_N 8192
#define NT    256
#define PHY(i) ((i) + ((i) >> 6))

typedef float v2f __attribute__((ext_vector_type(2)));
typedef float v4f __attribute__((ext_vector_type(4)));

__device__ __forceinline__ v2f cmul(v2f a, v2f b){
  v2f t, d;
  asm("v_pk_mul_f32 %0, %1, %2 op_sel:[0,0] op_sel_hi:[0,1]"
      : "=&v"(t) : "v"(a), "v"(b));
  asm("v_pk_fma_f32 %0, %1, %2, %3 op_sel:[1,1,0] op_sel_hi:[1,0,1] neg_lo:[0,1,0]"
      : "=v"(d) : "v"(a), "v"(b), "v"(t));
  return d;
}

// d * W_32^j (or conj), j in [0,16), compile-time after unroll -> constants fold.
__device__ __forceinline__ v2f mul_w32(v2f d, int j, bool cj){
  if (j == 0) return d;
  if (j == 8) return cj ? (v2f){-d.y, d.x} : (v2f){d.y, -d.x};
  const float C[16] = {1.f, 0.98078528f, 0.92387953f, 0.83146961f, 0.70710678f,
                       0.55557023f, 0.38268343f, 0.19509032f, 0.f, -0.19509032f,
                       -0.38268343f, -0.55557023f, -0.70710678f, -0.83146961f,
                       -0.92387953f, -0.98078528f};
  const float S[16] = {0.f, -0.19509032f, -0.38268343f, -0.55557023f, -0.70710678f,
                       -0.83146961f, -0.92387953f, -0.98078528f, -1.f, -0.98078528f,
                       -0.92387953f, -0.83146961f, -0.70710678f, -0.55557023f,
                       -0.38268343f, -0.19509032f};
  v2f w = {C[j], cj ? -S[j] : S[j]};
  return cmul(d, w);
}

// DIF radix-2 stages, spans L..1 over SZ regs. Stage twiddle W_{2L}^j == W_32^{j*16/L}.
template<int SZ, int L>
__device__ __forceinline__ void dif_rec(v2f* r){
  #pragma unroll
  for (int g = 0; g < SZ; g += 2*L){
    #pragma unroll
    for (int j = 0; j < L; ++j){
      v2f u = r[g+j], v = r[g+j+L];
      r[g+j]   = u + v;
      r[g+j+L] = mul_w32(u - v, j*(16/L), false);
    }
  }
  if constexpr (L > 1) dif_rec<SZ, L/2>(r);
}

// Inverse DIT radix-2 stages, spans 1..SZ/2 (conjugate twiddles), unnormalized.
template<int SZ, int L>
__device__ __forceinline__ void dit_rec(v2f* r){
  #pragma unroll
  for (int g = 0; g < SZ; g += 2*L){
    #pragma unroll
    for (int j = 0; j < L; ++j){
      v2f a = r[g+j];
      v2f b = mul_w32(r[g+j+L], j*(16/L), true);
      r[g+j]   = a + b;
      r[g+j+L] = a - b;
    }
  }
  if constexpr (2*L < SZ) dit_rec<SZ, 2*L>(r);
}

__host__ __device__ constexpr int brev5(int k){
  return ((k&1)<<4) | ((k&2)<<2) | (k&4) | ((k&8)>>2) | ((k&16)>>4);
}

// r[brev5(k)] *= W_8192^{cbase*k} (or conj), k=1..31 (two half-chains for ILP).
__device__ __forceinline__ void twiddle_scale(v2f* r, int cbase, bool cj){
  float s, c;
  __sincosf((float)cbase * -7.6699039394282061e-4f, &s, &c);  // -2*pi/8192
  if (cj) s = -s;
  const v2f w1 = {c, s};
  v2f w2q = cmul(w1, w1);
  v2f w4q = cmul(w2q, w2q);
  v2f w8q = cmul(w4q, w4q);
  v2f w16 = cmul(w8q, w8q);
  v2f wa = w1;
  r[brev5(1)]  = cmul(r[brev5(1)],  wa);
  r[brev5(17)] = cmul(r[brev5(17)], cmul(w16, wa));
  #pragma unroll
  for (int k = 2; k <= 15; ++k){
    wa = cmul(wa, w1);
    r[brev5(k)]    = cmul(r[brev5(k)],    wa);
    r[brev5(k+16)] = cmul(r[brev5(k+16)], cmul(w16, wa));
  }
  r[brev5(16)] = cmul(r[brev5(16)], w16);
}

// r[brev3(k)] *= w1^k, k=1..7, w1 = W_8192^c (pass conj(w1) for inverse).
// brev3: 1->4, 2->2, 3->6, 4->1, 5->5, 6->3, 7->7.
__device__ __forceinline__ void tw8(v2f* r, v2f w1){
  v2f w2 = cmul(w1, w1);
  v2f w3 = cmul(w2, w1);
  v2f w4 = cmul(w2, w2);
  v2f w5 = cmul(w4, w1);
  v2f w6 = cmul(w4, w2);
  v2f w7 = cmul(w4, w3);
  r[4] = cmul(r[4], w1);
  r[2] = cmul(r[2], w2);
  r[6] = cmul(r[6], w3);
  r[1] = cmul(r[1], w4);
  r[5] = cmul(r[5], w5);
  r[3] = cmul(r[3], w6);
  r[7] = cmul(r[7], w7);
}

__global__ __launch_bounds__(NT, 2)
void fourier_filter_kernel(const float* __restrict__ x, float* __restrict__ out){
  __shared__ __half2 zs[FFT_N + FFT_N/64];   // 8320 * 4B = 32.5 KB (pad every 64)
  const int t = threadIdx.x;
  const long long pair = blockIdx.x;
  const float* r0 = x + pair * (2LL * FFT_N);
  const float* r1 = r0 + FFT_N;
  v2f r[32];

  // W_8192^1, W_8192^2 (for chain bases 4t+1, 4t+2, 4t+3)
  const v2f W1C = {0.9999997058629f, -7.669903187e-4f};
  const v2f W2C = {0.9999988234517f, -1.5339801863e-3f};

  // ---- fwd phase 1: 4 chains c=4t+e, FFT-8 over m (n = 4t+e+1024m) ----
  #pragma unroll
  for (int m = 0; m < 8; ++m){
    const int n = 4*t + (m << 10);
    const v4f a = *reinterpret_cast<const v4f*>(r0 + n);
    const v4f b = *reinterpret_cast<const v4f*>(r1 + n);
    r[0*8+m] = (v2f){a.x, b.x};
    r[1*8+m] = (v2f){a.y, b.y};
    r[2*8+m] = (v2f){a.z, b.z};
    r[3*8+m] = (v2f){a.w, b.w};
  }
  #pragma unroll
  for (int e = 0; e < 4; ++e) dif_rec<8, 4>(r + 8*e);
  {
    float s, c;
    __sincosf((float)(4*t) * -7.6699039394282061e-4f, &s, &c);
    v2f w0 = {c, s};
    v2f wA = cmul(w0, W1C);
    v2f wB = cmul(w0, W2C);
    v2f wC = cmul(wA, W2C);
    tw8(r + 0,  w0);
    tw8(r + 8,  wA);
    tw8(r + 16, wB);
    tw8(r + 24, wC);
  }
  #pragma unroll
  for (int e = 0; e < 4; ++e)
    #pragma unroll
    for (int m = 0; m < 8; ++m)
      zs[PHY(4*t + e + (m<<10))] = __floats2half2_rn(r[8*e+m].x, r[8*e+m].y);
  __syncthreads();

  // ---- fwd phase 2: chains {1024(t>>5) + (t&31) + 32m}, FFT-32 ----
  const int base2 = ((t >> 5) << 10) | (t & 31);
  #pragma unroll
  for (int m = 0; m < 32; ++m){
    float2 f = __half22float2(zs[PHY(base2 + (m<<5))]);
    r[m] = (v2f){f.x, f.y};
  }
  dif_rec<32, 16>(r);
  twiddle_scale(r, (t & 31) << 3, false);   // W_1024^{c2*k} = W_8192^{8*c2*k}
  #pragma unroll
  for (int m = 0; m < 32; ++m)
    zs[PHY(base2 + (m<<5))] = __floats2half2_rn(r[m].x, r[m].y);
  __syncthreads();

  // ---- phase 3: contiguous FFT-32 fwd + MASK + inv, fused in regs ----
  #pragma unroll
  for (int e = 0; e < 32; ++e){
    float2 f = __half22float2(zs[PHY((t<<5) + e)]);
    r[e] = (v2f){f.x, f.y};
  }
  dif_rec<32, 16>(r);
  #pragma unroll
  for (int e = 0; e < 32; ++e){
    const int v  = (t << 5) + e;
    const int k  = (int)(__brev((unsigned)v) >> 19);   // slot v holds bin brev13(v)
    const int kf = min(k, FFT_N - k);
    if (kf <= 819) r[e] = (v2f){0.f, 0.f};             // |freq| < 10 Hz
  }
  dit_rec<32, 1>(r);
  #pragma unroll
  for (int e = 0; e < 32; ++e)
    zs[PHY((t<<5) + e)] = __floats2half2_rn(r[e].x, r[e].y);
  __syncthreads();

  // ---- inv phase 2: conj pre-twiddle, DIT ----
  #pragma unroll
  for (int m = 0; m < 32; ++m){
    float2 f = __half22float2(zs[PHY(base2 + (m<<5))]);
    r[m] = (v2f){f.x, f.y};
  }
  twiddle_scale(r, (t & 31) << 3, true);
  dit_rec<32, 1>(r);
  #pragma unroll
  for (int m = 0; m < 32; ++m)
    zs[PHY(base2 + (m<<5))] = __floats2half2_rn(r[m].x, r[m].y);
  __syncthreads();

  // ---- inv phase 1: conj pre-twiddle, 4 x DIT-8, vec4 store ----
  #pragma unroll
  for (int e = 0; e < 4; ++e)
    #pragma unroll
    for (int m = 0; m < 8; ++m){
      float2 f = __half22float2(zs[PHY(4*t + e + (m<<10))]);
      r[8*e+m] = (v2f){f.x, f.y};
    }
  {
    float s, c;
    __sincosf((float)(4*t) * -7.6699039394282061e-4f, &s, &c);
    v2f w0 = {c, -s};                        // conj(W^{4t})
    const v2f W1Cc = {W1C.x, -W1C.y};
    const v2f W2Cc = {W2C.x, -W2C.y};
    v2f wA = cmul(w0, W1Cc);
    v2f wB = cmul(w0, W2Cc);
    v2f wC = cmul(wA, W2Cc);
    tw8(r + 0,  w0);
    tw8(r + 8,  wA);
    tw8(r + 16, wB);
    tw8(r + 24, wC);
  }
  #pragma unroll
  for (int e = 0; e < 4; ++e) dit_rec<8, 1>(r + 8*e);

  const float invn = 1.f / (float)FFT_N;
  float* o0 = out + pair * (2LL * FFT_N);
  float* o1 = o0 + FFT_N;
  #pragma unroll
  for (int m = 0; m < 8; ++m){
    const int n = 4*t + (m << 10);
    v4f a, b;
    a.x = r[0*8+m].x * invn;  b.x = r[0*8+m].y * invn;
    a.y = r[1*8+m].x * invn;  b.y = r[1*8+m].y * invn;
    a.z = r[2*8+m].x * invn;  b.z = r[2*8+m].y * invn;
    a.w = r[3*8+m].x * invn;  b.w = r[3*8+m].y * invn;
    __builtin_nontemporal_store(a, reinterpret_cast<v4f*>(o0 + n));
    __builtin_nontemporal_store(b, reinterpret_cast<v4f*>(o1 + n));
  }
}

extern "C" void kernel_launch(void* const* d_in, const int* in_sizes, int n_in,
                              void* d_out, int out_size, void* d_ws, size_t ws_size,
                              hipStream_t stream) {
  const float* x = (const float*)d_in[0];
  float* out = (float*)d_out;
  const int total  = in_sizes[0];              // 64*128*8192
  const int npairs = total / (2 * FFT_N);      // 4096 row pairs
  hipLaunchKernelGGL(fourier_filter_kernel, dim3(npairs), dim3(NT), 0, stream,
                     x, out);
}